// Round 2
// baseline (159.029 us; speedup 1.0000x reference)
//
#include <hip/hip_runtime.h>
#include <stdint.h>

static constexpr int Mrows = 16384;   // B*N = 64*256
static constexpr int Kdim  = 1024;    // L
static constexpr int Ncols = 512;     // OUT

typedef __attribute__((ext_vector_type(8))) short bf16x8;
typedef __attribute__((ext_vector_type(4))) float f32x4;

__device__ __forceinline__ unsigned short f2bf(float f) {
  unsigned u = __builtin_bit_cast(unsigned, f);
  u += 0x7FFFu + ((u >> 16) & 1u);          // RNE
  return (unsigned short)(u >> 16);
}
__device__ __forceinline__ unsigned f2bf2(float lo, float hi) {
  unsigned ul = __builtin_bit_cast(unsigned, lo);
  unsigned uh = __builtin_bit_cast(unsigned, hi);
  ul += 0x7FFFu + ((ul >> 16) & 1u);
  uh += 0x7FFFu + ((uh >> 16) & 1u);
  return (ul >> 16) | (uh & 0xFFFF0000u);
}

// async global->LDS, 16B per lane; LDS dest = uniform base + lane*16
__device__ __forceinline__ void gl2lds16(const void* g, void* l) {
  __builtin_amdgcn_global_load_lds(
      (const __attribute__((address_space(1))) void*)g,
      (__attribute__((address_space(3))) void*)l, 16, 0, 0);
}

// ---------------------------------------------------------------------------
// prep_w: 512 blocks: Wt[n][k] = bf16(0.5*(W_in+W_out)+W_root)^T.  ~7 MiB of
// traffic total -- a few microseconds.
// ---------------------------------------------------------------------------
__global__ __launch_bounds__(256) void prep_w(
    const float* __restrict__ Win, const float* __restrict__ Wout,
    const float* __restrict__ Wroot, unsigned short* __restrict__ Wt)
{
  __shared__ unsigned short lds[32 * 36];
  const int t  = threadIdx.x;
  const int b2 = blockIdx.x;
  const int tk0 = (b2 & 31) * 32;          // 1024/32 = 32 K-tiles
  const int tn0 = (b2 >> 5) * 32;          // 512/32  = 16 N-tiles
  {
    const int k  = t >> 3;                 // 0..31
    const int nq = (t & 7) * 4;            // 0,4,..,28
    const int gi = (tk0 + k) * Ncols + tn0 + nq;
    const float4 wi = *(const float4*)(Win + gi);
    const float4 wo = *(const float4*)(Wout + gi);
    const float4 wr = *(const float4*)(Wroot + gi);
    lds[(nq + 0) * 36 + k] = f2bf(0.5f * (wi.x + wo.x) + wr.x);
    lds[(nq + 1) * 36 + k] = f2bf(0.5f * (wi.y + wo.y) + wr.y);
    lds[(nq + 2) * 36 + k] = f2bf(0.5f * (wi.z + wo.z) + wr.z);
    lds[(nq + 3) * 36 + k] = f2bf(0.5f * (wi.w + wo.w) + wr.w);
  }
  __syncthreads();
  {
    const int n  = t >> 3;                 // 0..31
    const int k8 = (t & 7) * 4;            // 0,4,..,28
    const ushort4 v = *(const ushort4*)&lds[n * 36 + k8];
    *(ushort4*)(Wt + (size_t)(tn0 + n) * Kdim + tk0 + k8) = v;
  }
}

// ---------------------------------------------------------------------------
// gemm_fused: Y[16384][512] = bf16(x) @ Wt^T + bias.  128x128 tile, BK=32,
// 4 waves 2x2, each wave 64x64 (4x4 mfma_f32_16x16x32_bf16).
//
// Pipeline (1 barrier/iter, counted vmcnt -- never 0 in the loop):
//   iter t: [barrier passed -> buffers (t+1)&1 free]
//     1. gl2lds B(t+1) -> Bs[nxt]            (2 vm ops, full-iter cover)
//        sched_barrier(0): pins issue order so the fixed vmcnt(4) below
//        provably drains THESE two (A(t+2) loads must stay newer).
//     2. ds_read frags from As[cur]/Bs[cur]
//     3. pack A(t+1) regs (loaded at t-1, ~1-iter cover) -> ds_write As[nxt]
//     4. issue A(t+2) f32 loads (4 vm ops) into the other reg set
//     5. 16x MFMA
//     6. s_waitcnt vmcnt(4) lgkmcnt(0); s_barrier
//        -> B(t+1) landed, A ds_writes landed, A(t+2) still in flight.
// Reg sets S/T are statically named (rule #20); manual unroll-by-2 rotates.
// Swizzle (slot s of row r holds k-chunk s^((r>>1)&3)) identical to the
// harness-verified layout.
// ---------------------------------------------------------------------------
__global__ __launch_bounds__(256, 2) void gemm_fused(
    const float* __restrict__ x, const unsigned short* __restrict__ Wt,
    const float* __restrict__ b_in, const float* __restrict__ b_out,
    const float* __restrict__ b_root, float* __restrict__ Y)
{
  constexpr int BUF = 128 * 32;            // shorts per buffer (8 KB)
  __shared__ __attribute__((aligned(16))) short As[2 * BUF];
  __shared__ __attribute__((aligned(16))) short Bs[2 * BUF];

  const int bid = blockIdx.x;
  const int m0 = (bid & 127) * 128;
  const int n0 = (bid >> 7) * 128;

  const int t    = threadIdx.x;
  const int lane = t & 63;
  const int w    = t >> 6;
  const int wm   = w >> 1;
  const int wn   = w & 1;
  const int quad = lane >> 4;
  const int lm   = lane & 15;

  // --- staging addresses: each wave covers 32 rows of A and 32 rows of B
  const int sr = lane >> 2;                  // row within 16-row group
  const int ss = lane & 3;                   // LDS 16B slot within row
  const int sc = ss ^ ((sr >> 1) & 3);       // global chunk fetched into it
  const float* gX          = x  + (size_t)(m0 + w * 32 + sr) * Kdim + sc * 8;
  const unsigned short* gB = Wt + (size_t)(n0 + w * 32 + sr) * Kdim + sc * 8;
  short* const lA  = &As[(w * 32 + sr) * 32 + ss * 8];   // per-lane ds_write dest
  short* const lB0 = &Bs[(w * 32) * 32];                 // wave-uniform gl2lds base
  short* const lB1 = lB0 + 16 * 32;
  const int rowK = 16 * Kdim;                // +16 rows in global (elems)

  // --- fragment addresses (unchanged layout)
  const int slot = quad ^ ((lm >> 1) & 3);
  const int aoff = (wm * 64 + lm) * 32 + slot * 8;
  const int boff = (wn * 64 + lm) * 32 + slot * 8;

  f32x4 acc[4][4] = {};
  float4 S0, S1, S2, S3, T0, T1, T2, T3;

#define LOADA(P0, P1, P2, P3, IDX) do {                                   \
    const float* gx_ = gX + (IDX) * 32;                                   \
    P0 = *(const float4*)(gx_);                                           \
    P1 = *(const float4*)(gx_ + 4);                                       \
    P2 = *(const float4*)(gx_ + rowK);                                    \
    P3 = *(const float4*)(gx_ + rowK + 4);                                \
  } while (0)

#define PACKA(P0, P1, P2, P3, NXT) do {                                   \
    uint4 pa_, pb_;                                                       \
    pa_.x = f2bf2(P0.x, P0.y); pa_.y = f2bf2(P0.z, P0.w);                 \
    pa_.z = f2bf2(P1.x, P1.y); pa_.w = f2bf2(P1.z, P1.w);                 \
    pb_.x = f2bf2(P2.x, P2.y); pb_.y = f2bf2(P2.z, P2.w);                 \
    pb_.z = f2bf2(P3.x, P3.y); pb_.w = f2bf2(P3.z, P3.w);                 \
    *(uint4*)(lA + (NXT) * BUF)           = pa_;                          \
    *(uint4*)(lA + (NXT) * BUF + 16 * 32) = pb_;                          \
  } while (0)

#define SYNC() do {                                                       \
    asm volatile("s_waitcnt vmcnt(4) lgkmcnt(0)" ::: "memory");           \
    __builtin_amdgcn_s_barrier();                                         \
    __builtin_amdgcn_sched_barrier(0);                                    \
  } while (0)

#define KSTEP(TT, QA0, QA1, QA2, QA3, RA0, RA1, RA2, RA3) do {            \
    const int cur_ = (TT) & 1, nxt_ = cur_ ^ 1;                           \
    gl2lds16(gB + ((TT) + 1) * 32,        lB0 + nxt_ * BUF);              \
    gl2lds16(gB + ((TT) + 1) * 32 + rowK, lB1 + nxt_ * BUF);              \
    __builtin_amdgcn_sched_barrier(0);  /* keep gl2lds oldest in vm queue */ \
    bf16x8 af[4], bfr[4];                                                 \
    _Pragma("unroll") for (int i = 0; i < 4; ++i)                         \
      af[i]  = *(const bf16x8*)&As[cur_ * BUF + aoff + i * 16 * 32];      \
    _Pragma("unroll") for (int j = 0; j < 4; ++j)                         \
      bfr[j] = *(const bf16x8*)&Bs[cur_ * BUF + boff + j * 16 * 32];      \
    PACKA(QA0, QA1, QA2, QA3, nxt_);                                      \
    { int ld_ = (TT) + 2; if (ld_ > 31) ld_ = 31;                         \
      LOADA(RA0, RA1, RA2, RA3, ld_); }                                   \
    _Pragma("unroll") for (int i = 0; i < 4; ++i)                         \
      _Pragma("unroll") for (int j = 0; j < 4; ++j)                       \
        acc[i][j] = __builtin_amdgcn_mfma_f32_16x16x32_bf16(              \
            af[i], bfr[j], acc[i][j], 0, 0, 0);                           \
    SYNC();                                                               \
  } while (0)

  // prologue: A(0),A(1) reg loads; B(0) gl2lds; pack A(0) -> As[0]
  LOADA(S0, S1, S2, S3, 0);
  gl2lds16(gB, lB0);
  gl2lds16(gB + rowK, lB1);
  __builtin_amdgcn_sched_barrier(0);
  LOADA(T0, T1, T2, T3, 1);
  PACKA(S0, S1, S2, S3, 0);
  SYNC();                                    // vmcnt(4): B(0) landed, A(1) in flight

  #pragma unroll 1
  for (int it = 0; it < 30; it += 2) {
    KSTEP(it,     T0, T1, T2, T3, S0, S1, S2, S3);
    KSTEP(it + 1, S0, S1, S2, S3, T0, T1, T2, T3);
  }
  KSTEP(30, T0, T1, T2, T3, S0, S1, S2, S3);

  // tail: it = 31 -> buffers [1], no prefetch, no trailing barrier
  {
    bf16x8 af[4], bfr[4];
    #pragma unroll
    for (int i = 0; i < 4; ++i) af[i]  = *(const bf16x8*)&As[BUF + aoff + i * 16 * 32];
    #pragma unroll
    for (int j = 0; j < 4; ++j) bfr[j] = *(const bf16x8*)&Bs[BUF + boff + j * 16 * 32];
    #pragma unroll
    for (int i = 0; i < 4; ++i)
      #pragma unroll
      for (int j = 0; j < 4; ++j)
        acc[i][j] = __builtin_amdgcn_mfma_f32_16x16x32_bf16(af[i], bfr[j], acc[i][j], 0, 0, 0);
  }

#undef KSTEP
#undef SYNC
#undef PACKA
#undef LOADA

  // epilogue: D[row=(lane>>4)*4+reg][col=lane&15] per 16x16 tile; bias fused
  #pragma unroll
  for (int j = 0; j < 4; ++j) {
    const int gc = n0 + wn * 64 + j * 16 + lm;
    const float bias = 0.5f * (b_in[gc] + b_out[gc]) + b_root[gc];
    #pragma unroll
    for (int i = 0; i < 4; ++i) {
      const int gr = m0 + wm * 64 + i * 16 + quad * 4;
      float* yp = Y + (size_t)gr * Ncols + gc;
      #pragma unroll
      for (int r = 0; r < 4; ++r)
        yp[(size_t)r * Ncols] = acc[i][j][r] + bias;
    }
  }
}

// ---------------------------------------------------------------------------
extern "C" void kernel_launch(void* const* d_in, const int* in_sizes, int n_in,
                              void* d_out, int out_size, void* d_ws, size_t ws_size,
                              hipStream_t stream)
{
  const float* x      = (const float*)d_in[0];
  // d_in[1] = At : dead input (ChebConv K=1 -> no neighbor aggregation)
  const float* W_in   = (const float*)d_in[2];
  const float* b_in   = (const float*)d_in[3];
  const float* W_out  = (const float*)d_in[4];
  const float* b_out  = (const float*)d_in[5];
  const float* W_root = (const float*)d_in[6];
  const float* b_root = (const float*)d_in[7];
  float* y = (float*)d_out;

  unsigned short* Wt = (unsigned short*)d_ws;   // 1 MiB only

  prep_w<<<dim3(512), dim3(256), 0, stream>>>(W_in, W_out, W_root, Wt);
  gemm_fused<<<dim3(512), dim3(256), 0, stream>>>(x, Wt, b_in, b_out, b_root, y);
}

// Round 3
// 155.626 us; speedup vs baseline: 1.0219x; 1.0219x over previous
//
#include <hip/hip_runtime.h>
#include <stdint.h>

static constexpr int Mrows = 16384;   // B*N = 64*256
static constexpr int Kdim  = 1024;    // L
static constexpr int Ncols = 512;     // OUT

static constexpr int TM  = 64;        // gemm m-tile
static constexpr int TN  = 128;       // gemm n-tile
static constexpr int BK  = 32;
static constexpr int NMT = Mrows / TM;   // 256
static constexpr int NNT = Ncols / TN;   // 4
static constexpr int NKT = Kdim / BK;    // 32

typedef __attribute__((ext_vector_type(8))) short bf16x8;
typedef __attribute__((ext_vector_type(4))) float f32x4;

__device__ __forceinline__ unsigned short f2bf(float f) {
  unsigned u = __builtin_bit_cast(unsigned, f);
  u += 0x7FFFu + ((u >> 16) & 1u);          // RNE
  return (unsigned short)(u >> 16);
}
__device__ __forceinline__ unsigned f2bf2(float lo, float hi) {
  unsigned ul = __builtin_bit_cast(unsigned, lo);
  unsigned uh = __builtin_bit_cast(unsigned, hi);
  ul += 0x7FFFu + ((ul >> 16) & 1u);
  uh += 0x7FFFu + ((uh >> 16) & 1u);
  return (ul >> 16) | (uh & 0xFFFF0000u);
}

// async global->LDS, 16B per lane; LDS dest = uniform base + lane*16
__device__ __forceinline__ void gl2lds16(const void* g, void* l) {
  __builtin_amdgcn_global_load_lds(
      (const __attribute__((address_space(1))) void*)g,
      (__attribute__((address_space(3))) void*)l, 16, 0, 0);
}

// ---------------------------------------------------------------------------
// prep (grid 1024):
//  blocks [0,512): tile-pack x -> Xpack.  Block b owns 32 contiguous m-rows
//    (a contiguous 128 KB span of x).  Image (mt,kt) = 64 rows x 32 k bf16,
//    2048 shorts CONTIGUOUS, with the gemm LDS swizzle PRE-BAKED:
//    slot s of image row r holds k-chunk s^((r>>1)&3).  So the gemm's
//    A-staging is a pure linear memcpy image->LDS (global_load_lds).
//  blocks [512,1024): Wt[n][k] = bf16(0.5*(W_in+W_out)+W_root)^T (unchanged).
// ---------------------------------------------------------------------------
__global__ __launch_bounds__(256) void prep(
    const float* __restrict__ x,
    const float* __restrict__ Win, const float* __restrict__ Wout,
    const float* __restrict__ Wroot,
    unsigned short* __restrict__ Xpack, unsigned short* __restrict__ Wt)
{
  const int bid = blockIdx.x;
  const int t = threadIdx.x;
  if (bid < 512) {
    const int mt = bid >> 1;
    const int h  = bid & 1;                 // 32-row half of the 64-row tile
    const float* xrow0 = x + (size_t)bid * 32 * Kdim;
    unsigned short* img0 = Xpack + (size_t)mt * NKT * 2048;
    #pragma unroll
    for (int j = 0; j < 16; ++j) {
      const int p  = j * 256 + t;           // pair index in [0,4096)
      const int rr = p >> 7;                // row in [0,32), 128 pairs/row
      const int q  = p & 127;               // 32B-pair within the row
      const int kt = q >> 2;                // k-tile
      const int c  = q & 3;                 // k-chunk within tile
      const int ri = h * 32 + rr;           // image row
      const int s  = c ^ ((rr >> 1) & 3);   // pre-baked swizzle slot
      const float* src = xrow0 + (size_t)rr * Kdim + q * 8;
      const float4 lo = *(const float4*)(src);
      const float4 hi = *(const float4*)(src + 4);
      uint4 pk;
      pk.x = f2bf2(lo.x, lo.y); pk.y = f2bf2(lo.z, lo.w);
      pk.z = f2bf2(hi.x, hi.y); pk.w = f2bf2(hi.z, hi.w);
      *(uint4*)(img0 + (size_t)kt * 2048 + ri * 32 + s * 8) = pk;
    }
  } else {
    __shared__ unsigned short lds[32 * 36];
    const int b2 = bid - 512;
    const int tk0 = (b2 & 31) * 32;          // 1024/32 = 32 K-tiles
    const int tn0 = (b2 >> 5) * 32;          // 512/32  = 16 N-tiles
    {
      const int k  = t >> 3;                 // 0..31
      const int nq = (t & 7) * 4;            // 0,4,..,28
      const int gi = (tk0 + k) * Ncols + tn0 + nq;
      const float4 wi = *(const float4*)(Win + gi);
      const float4 wo = *(const float4*)(Wout + gi);
      const float4 wr = *(const float4*)(Wroot + gi);
      lds[(nq + 0) * 36 + k] = f2bf(0.5f * (wi.x + wo.x) + wr.x);
      lds[(nq + 1) * 36 + k] = f2bf(0.5f * (wi.y + wo.y) + wr.y);
      lds[(nq + 2) * 36 + k] = f2bf(0.5f * (wi.z + wo.z) + wr.z);
      lds[(nq + 3) * 36 + k] = f2bf(0.5f * (wi.w + wo.w) + wr.w);
    }
    __syncthreads();
    {
      const int n  = t >> 3;                 // 0..31
      const int k8 = (t & 7) * 4;            // 0,4,..,28
      const ushort4 v = *(const ushort4*)&lds[n * 36 + k8];
      *(ushort4*)(Wt + (size_t)(tn0 + n) * Kdim + tk0 + k8) = v;
    }
  }
}

// ---------------------------------------------------------------------------
// gemm: Y[16384][512] = A @ Wt^T + bias.  64x128 tile, BK=32, 4 waves 2x2,
// wave = 32x64 output (2x4 mfma_f32_16x16x32_bf16).  Grid 1024 -> 4 blocks/CU
// (4 independent barrier groups, 16 waves/CU) vs 2 before.
//
// Staging is ALL global_load_lds (3 ops/wave/iter: 1x A from the contiguous
// pre-swizzled Xpack image, 2x B from Wt), triple-buffered LDS, 2 tiles
// prefetched ahead.  Per-wave VM queue holds exactly two tiles' staging, so
// the end-of-iter wait is s_waitcnt vmcnt(3): drains tile t+1, leaves t+2 in
// flight.  No per-lane VMEM and no ds_write in the loop -> the count is
// exact and no lgkm drain is needed at the barrier (compiler handles the
// frag ds_read -> MFMA waits).
// Block->tile map keeps the 4 n-sharers of each A-image on ONE XCD:
//   xcd = bid&7, slot = bid>>3, nt = slot&3, mt = xcd*32 + (slot>>2).
// ---------------------------------------------------------------------------
__global__ __launch_bounds__(256, 4) void gemm_bf16(
    const unsigned short* __restrict__ Xpack, const unsigned short* __restrict__ Wt,
    const float* __restrict__ b_in, const float* __restrict__ b_out,
    const float* __restrict__ b_root, float* __restrict__ Y)
{
  constexpr int ABUF = TM * BK;              // 2048 shorts (4 KB)
  constexpr int BBUF = TN * BK;              // 4096 shorts (8 KB)
  __shared__ __attribute__((aligned(16))) short As[3 * ABUF];
  __shared__ __attribute__((aligned(16))) short Bs[3 * BBUF];

  const int bid  = blockIdx.x;
  const int xcd  = bid & 7;
  const int slot = bid >> 3;
  const int nt   = slot & 3;
  const int mt   = xcd * 32 + (slot >> 2);
  const int m0   = mt * TM;
  const int n0   = nt * TN;

  const int t    = threadIdx.x;
  const int lane = t & 63;
  const int w    = t >> 6;
  const int wm   = w >> 1;                   // 0..1 : 32-row m-slice
  const int wn   = w & 1;                    // 0..1 : 64-col n-slice
  const int quad = lane >> 4;
  const int lm   = lane & 15;

  // --- A staging: linear copy of the pre-swizzled image; wave w covers
  //     image bytes [w*1024, w*1024+1024)
  const unsigned short* gA = Xpack + (size_t)mt * NKT * 2048 + w * 512 + lane * 8;
  short* const lA = &As[w * 512];            // + buf*ABUF at use

  // --- B staging (verified layout): wave w covers B rows w*32..w*32+31,
  //     slot s of row r holds chunk s^((r>>1)&3) via swizzled global addr
  const int sr = lane >> 2;
  const int ss = lane & 3;
  const int sc = ss ^ ((sr >> 1) & 3);
  const unsigned short* gB = Wt + (size_t)(n0 + w * 32 + sr) * Kdim + sc * 8;
  short* const lB0 = &Bs[(w * 32) * 32];
  short* const lB1 = lB0 + 16 * 32;
  const int rowK = 16 * Kdim;

  // --- fragment addresses
  const int fslot = quad ^ ((lm >> 1) & 3);
  const int aoff = (wm * 32 + lm) * 32 + fslot * 8;   // + i*512, i in {0,1}
  const int boff = (wn * 64 + lm) * 32 + fslot * 8;   // + j*512, j in 0..3

  f32x4 acc[2][4] = {};

#define STAGE(TT, BUF) do {                                               \
    gl2lds16(gA + (size_t)(TT) * 2048, lA + (BUF) * ABUF);                \
    gl2lds16(gB + (TT) * 32,        lB0 + (BUF) * BBUF);                  \
    gl2lds16(gB + (TT) * 32 + rowK, lB1 + (BUF) * BBUF);                  \
  } while (0)

#define COMPUTE(BUF) do {                                                 \
    bf16x8 af[2], bfr[4];                                                 \
    _Pragma("unroll") for (int i = 0; i < 2; ++i)                         \
      af[i]  = *(const bf16x8*)&As[(BUF) * ABUF + aoff + i * 512];        \
    _Pragma("unroll") for (int j = 0; j < 4; ++j)                         \
      bfr[j] = *(const bf16x8*)&Bs[(BUF) * BBUF + boff + j * 512];        \
    _Pragma("unroll") for (int i = 0; i < 2; ++i)                         \
      _Pragma("unroll") for (int j = 0; j < 4; ++j)                       \
        acc[i][j] = __builtin_amdgcn_mfma_f32_16x16x32_bf16(              \
            af[i], bfr[j], acc[i][j], 0, 0, 0);                           \
  } while (0)

  // prologue: two tiles in flight
  STAGE(0, 0);
  STAGE(1, 1);
  asm volatile("s_waitcnt vmcnt(3)" ::: "memory");   // tile 0 landed
  __builtin_amdgcn_s_barrier();

  int b0 = 0, b1 = 1, b2 = 2;                // cur, next, stage targets
  #pragma unroll 1
  for (int it = 0; it < 30; ++it) {
    STAGE(it + 2, b2);
    __builtin_amdgcn_sched_barrier(0);       // staging issued before compute
    COMPUTE(b0);
    asm volatile("s_waitcnt vmcnt(3)" ::: "memory");  // tile it+1 landed
    __builtin_amdgcn_s_barrier();
    const int tmp = b0; b0 = b1; b1 = b2; b2 = tmp;
  }
  // it = 30: nothing left to stage; drain tile 31
  COMPUTE(b0);
  asm volatile("s_waitcnt vmcnt(0)" ::: "memory");
  __builtin_amdgcn_s_barrier();
  // it = 31
  COMPUTE(b1);

#undef COMPUTE
#undef STAGE

  // epilogue: D[row=(lane>>4)*4+reg][col=lane&15] per 16x16 tile; bias fused
  #pragma unroll
  for (int j = 0; j < 4; ++j) {
    const int gc = n0 + wn * 64 + j * 16 + lm;
    const float bias = 0.5f * (b_in[gc] + b_out[gc]) + b_root[gc];
    #pragma unroll
    for (int i = 0; i < 2; ++i) {
      const int gr = m0 + wm * 32 + i * 16 + quad * 4;
      float* yp = Y + (size_t)gr * Ncols + gc;
      #pragma unroll
      for (int r = 0; r < 4; ++r)
        yp[(size_t)r * Ncols] = acc[i][j][r] + bias;
    }
  }
}

// ---------------------------------------------------------------------------
extern "C" void kernel_launch(void* const* d_in, const int* in_sizes, int n_in,
                              void* d_out, int out_size, void* d_ws, size_t ws_size,
                              hipStream_t stream)
{
  const float* x      = (const float*)d_in[0];
  // d_in[1] = At : dead input (ChebConv K=1 -> no neighbor aggregation)
  const float* W_in   = (const float*)d_in[2];
  const float* b_in   = (const float*)d_in[3];
  const float* W_out  = (const float*)d_in[4];
  const float* b_out  = (const float*)d_in[5];
  const float* W_root = (const float*)d_in[6];
  const float* b_root = (const float*)d_in[7];
  float* y = (float*)d_out;

  unsigned short* Xpack = (unsigned short*)d_ws;                      // 32 MiB
  unsigned short* Wt = (unsigned short*)d_ws + (size_t)Mrows * Kdim;  // 1 MiB

  prep<<<dim3(1024), dim3(256), 0, stream>>>(x, W_in, W_out, W_root, Xpack, Wt);
  gemm_bf16<<<dim3(1024), dim3(256), 0, stream>>>(Xpack, Wt, b_in, b_out, b_root, y);
}